// Round 18
// baseline (535.775 us; speedup 1.0000x reference)
//
#include <hip/hip_runtime.h>

#define NPRI 21504
#define BATCH 64
#define KTOP 1024
#define NCH 21

typedef unsigned long long u64;
typedef unsigned int u32;

// correctly-rounded f32 exp via f64 libm exp (validated: absmax 3e-8)
__device__ __forceinline__ float crexpf(float x) { return (float)exp((double)x); }

__device__ __forceinline__ u64 readlane64(u64 v, int lane) {
  int lo = __builtin_amdgcn_readlane((int)(u32)v, lane);
  int hi = __builtin_amdgcn_readlane((int)(u32)(v >> 32), lane);
  return ((u64)(u32)hi << 32) | (u64)(u32)lo;
}

// Key packing (validated): key = (score_bits<<15) | (NPRI-1-idx). Unique keys;
// desc u64 order == (score desc, idx asc) == lax.top_k stable order => any
// correct top-1024 structure is bit-exact.

// K1: fused score + per-chunk bitonic sort (r12-validated, 1344 blocks, 8 KB).
__global__ __launch_bounds__(256) void k_sort(const float* __restrict__ confs,
                                              u64* __restrict__ keyG) {
  const int b = blockIdx.x / NCH;
  const int c = blockIdx.x % NCH;
  __shared__ u64 ks[KTOP];
  const float2* cf = (const float2*)confs + (size_t)b * NPRI + c * KTOP;
  for (int i = threadIdx.x; i < KTOP; i += 256) {
    float2 v = cf[i];
    float m = fmaxf(v.x, v.y);
    float e0 = crexpf(v.x - m);
    float e1 = crexpf(v.y - m);
    float s = e1 / (e0 + e1);          // exact f32 steps (validated)
    int idx = c * KTOP + i;
    ks[i] = ((u64)__float_as_uint(s) << 15) | (u64)(NPRI - 1 - idx);
  }
  for (int k = 2; k <= KTOP; k <<= 1) {
    for (int j = k >> 1; j > 0; j >>= 1) {
      __syncthreads();
      for (int l = threadIdx.x; l < KTOP; l += 256) {
        int p = l ^ j;
        if (p > l) {
          u64 a = ks[l], q = ks[p];
          bool up = ((l & k) == 0);
          if ((a > q) != up) { ks[l] = q; ks[p] = a; }
        }
      }
    }
  }
  __syncthreads();
  u64* dst = keyG + (size_t)b * NPRI + (size_t)c * KTOP;
  for (int i = threadIdx.x; i < KTOP; i += 256) dst[i] = ks[i];
}

// K2: 3 blocks/image: serially merge 7 runs -> top-1024 (r17-validated).
__global__ __launch_bounds__(256) void k_merge7(const u64* __restrict__ keyG,
                                                u64* __restrict__ midG) {
  const int b = blockIdx.x / 3;
  const int p3 = blockIdx.x % 3;
  __shared__ u64 A[KTOP];
  __shared__ u64 Bv[KTOP];
  const u64* src = keyG + ((size_t)b * NCH + p3 * 7) * KTOP;
  for (int i = threadIdx.x; i < KTOP; i += 256) A[i] = src[i];
  for (int c = 1; c < 7; c++) {
    __syncthreads();
    for (int i = threadIdx.x; i < KTOP; i += 256)
      Bv[i] = src[(size_t)c * KTOP + (KTOP - 1 - i)];   // reversed: asc
    __syncthreads();
    for (int i = threadIdx.x; i < KTOP; i += 256)
      if (Bv[i] > A[i]) A[i] = Bv[i];                    // half-cleaner
    for (int j = KTOP / 2; j > 0; j >>= 1) {             // clean -> desc
      __syncthreads();
      for (int l = threadIdx.x; l < KTOP; l += 256) {
        int p = l ^ j;
        if (p > l) {
          u64 a = A[l], q = A[p];
          if (a < q) { A[l] = q; A[p] = a; }
        }
      }
    }
  }
  __syncthreads();
  u64* d = midG + ((size_t)b * 3 + p3) * KTOP;
  for (int i = threadIdx.x; i < KTOP; i += 256) d[i] = A[i];
}

// K3: per image: merge 3 mids -> top-1024, then validated decode + valid-ballot.
__global__ __launch_bounds__(256) void k_merge3(const u64* __restrict__ midG,
                                                const float* __restrict__ locs,
                                                const float* __restrict__ priors,
                                                float* __restrict__ boxF,
                                                float* __restrict__ scoreF,
                                                u64* __restrict__ validW) {
  const int b = blockIdx.x;
  const int t = threadIdx.x;
  __shared__ u64 A[KTOP];
  __shared__ u64 Bv[KTOP];
  const u64* src = midG + (size_t)b * 3 * KTOP;
  for (int i = t; i < KTOP; i += 256) A[i] = src[i];
  for (int c = 1; c < 3; c++) {
    __syncthreads();
    for (int i = t; i < KTOP; i += 256)
      Bv[i] = src[(size_t)c * KTOP + (KTOP - 1 - i)];
    __syncthreads();
    for (int i = t; i < KTOP; i += 256)
      if (Bv[i] > A[i]) A[i] = Bv[i];
    for (int j = KTOP / 2; j > 0; j >>= 1) {
      __syncthreads();
      for (int l = t; l < KTOP; l += 256) {
        int p = l ^ j;
        if (p > l) {
          u64 a = A[l], q = A[p];
          if (a < q) { A[l] = q; A[p] = a; }
        }
      }
    }
  }
  __syncthreads();
  // decode top-1024: f32-stepwise (identical expressions to validated round 7)
  for (int i = t; i < KTOP; i += 256) {
    u64 K = A[i];
    float sv = __uint_as_float((u32)(K >> 15));
    int idx = NPRI - 1 - (int)(K & 0x7FFFu);
    float4 lo = ((const float4*)locs)[(size_t)b * NPRI + idx];
    float4 pr = ((const float4*)priors)[idx];
    float cx = pr.x + (lo.x * 0.1f) * pr.z;
    float cy = pr.y + (lo.y * 0.1f) * pr.w;
    float w  = pr.z * crexpf(lo.z * 0.2f);
    float h  = pr.w * crexpf(lo.w * 0.2f);
    float x1 = cx - w * 0.5f;
    float y1 = cy - h * 0.5f;
    float x2 = x1 + w;
    float y2 = y1 + h;
    size_t o = (size_t)b * KTOP + i;
    boxF[o * 4 + 0] = x1;
    boxF[o * 4 + 1] = y1;
    boxF[o * 4 + 2] = x2;
    boxF[o * 4 + 3] = y2;
    scoreF[o] = sv;
    u64 mask = __ballot(sv > 0.5f);       // wave covers group i>>6
    if ((t & 63) == 0) validW[(size_t)b * 16 + (i >> 6)] = mask;
  }
}

// K4: FUSED lazy-IoU greedy NMS. Per group g:
//  (1) diag words via per-wave ballot (wave v: rows v*16..v*16+15; lane j does
//      IoU(i, g*64+j) — identical f32 expressions to the validated k_iou);
//  (2) wave-0 ctz+readlane chain (r12-validated logic, byte-identical);
//  (3) kept rows only: wave v owns future words w=g+1+v (mod 4 step), lane j
//      does IoU(kept_i, w*64+j), ballot -> OR into remv[w] (disjoint w/wave).
// No sup matrix in HBM; suppression decisions bit-identical.
__global__ __launch_bounds__(256) void k_nms(const float* __restrict__ boxF,
                                             const float* __restrict__ scoreF,
                                             const u64* __restrict__ validW,
                                             float* __restrict__ out) {
  const int b = blockIdx.x;
  const int t = threadIdx.x;
  const int lane = t & 63;
  const int v = t >> 6;                // wave 0..3
  __shared__ float X1[KTOP], Y1[KTOP], X2[KTOP], Y2[KTOP], AR[KTOP];  // 20 KB
  __shared__ u64 diagW[64];
  __shared__ u64 remv[16], keepW[16], vW[16];
  const float4* bb = (const float4*)(boxF + (size_t)b * KTOP * 4);
  for (int i = t; i < KTOP; i += 256) {
    float4 q = bb[i];
    X1[i] = q.x; Y1[i] = q.y; X2[i] = q.z; Y2[i] = q.w;
    AR[i] = fmaxf(q.z - q.x, 0.0f) * fmaxf(q.w - q.y, 0.0f);
  }
  if (t < 16) { remv[t] = 0; vW[t] = validW[(size_t)b * 16 + t]; }
  __syncthreads();
  for (int g = 0; g < 16; g++) {
    // (1) intra-group diag via ballot; SoA reads: lane-consecutive f32 (free)
    {
      int j = g * 64 + lane;
      float xj1 = X1[j], yj1 = Y1[j], xj2 = X2[j], yj2 = Y2[j], aj = AR[j];
      for (int rr = 0; rr < 16; rr++) {
        int r = v * 16 + rr;
        int i = g * 64 + r;
        float x1 = X1[i], y1 = Y1[i], x2 = X2[i], y2 = Y2[i], a = AR[i]; // bcast
        float lx = fmaxf(x1, xj1), ly = fmaxf(y1, yj1);
        float rx = fminf(x2, xj2), ry = fminf(y2, yj2);
        float iw = fmaxf(rx - lx, 0.0f), ih = fmaxf(ry - ly, 0.0f);
        float inter = iw * ih;
        float uni = (a + aj) - inter;
        u64 word = __ballot(inter / fmaxf(uni, 1e-9f) > 0.4f);
        if (lane == 0)
          diagW[r] = (r == 63) ? 0ULL : (word & (~0ULL << (r + 1)));   // j > i
      }
    }
    __syncthreads();
    // (2) chain (r12-validated)
    if (v == 0) {
      u64 diag = diagW[lane];
      u64 alive = vW[g] & ~remv[g];
      u64 keep = 0, m = alive;
      while (m) {
        int i = __builtin_ctzll(m);
        keep |= (1ULL << i);
        alive &= ~readlane64(diag, i);
        m = (i == 63) ? 0ULL : (alive & (~0ULL << (i + 1)));
      }
      if (lane == 0) keepW[g] = keep;
    }
    __syncthreads();
    // (3) kept rows suppress future words (lazy IoU)
    {
      u64 kw = keepW[g];                 // uniform broadcast
      for (int w = g + 1 + v; w < 16; w += 4) {
        int j = w * 64 + lane;
        float xj1 = X1[j], yj1 = Y1[j], xj2 = X2[j], yj2 = Y2[j], aj = AR[j];
        u64 acc = 0, m = kw;
        while (m) {
          int i0 = __builtin_ctzll(m);
          m &= m - 1;
          int i = g * 64 + i0;
          float x1 = X1[i], y1 = Y1[i], x2 = X2[i], y2 = Y2[i], a = AR[i];
          float lx = fmaxf(x1, xj1), ly = fmaxf(y1, yj1);
          float rx = fminf(x2, xj2), ry = fminf(y2, yj2);
          float iw = fmaxf(rx - lx, 0.0f), ih = fmaxf(ry - ly, 0.0f);
          float inter = iw * ih;
          float uni = (a + aj) - inter;
          acc |= __ballot(inter / fmaxf(uni, 1e-9f) > 0.4f);
        }
        if (lane == 0 && acc) remv[w] |= acc;   // only wave v writes this w
      }
    }
    __syncthreads();   // remv visible for next group's chain
  }
  const float* sc = scoreF + (size_t)b * KTOP;
  for (int i = t; i < KTOP; i += 256) {
    float kf = ((keepW[i >> 6] >> (i & 63)) & 1ULL) ? 1.0f : 0.0f;
    size_t o5 = ((size_t)b * KTOP + i) * 5;
    out[o5 + 0] = X1[i] * kf;
    out[o5 + 1] = Y1[i] * kf;
    out[o5 + 2] = X2[i] * kf;
    out[o5 + 3] = Y2[i] * kf;
    out[o5 + 4] = sc[i] * kf;
    out[(size_t)BATCH * KTOP * 5 + (size_t)b * KTOP + i] = kf;
  }
}

extern "C" void kernel_launch(void* const* d_in, const int* in_sizes, int n_in,
                              void* d_out, int out_size, void* d_ws, size_t ws_size,
                              hipStream_t stream) {
  const float* locs = nullptr;
  const float* confs = nullptr;
  const float* priors = nullptr;
  for (int i = 0; i < n_in; i++) {
    if (in_sizes[i] == BATCH * NPRI * 4) locs = (const float*)d_in[i];
    else if (in_sizes[i] == BATCH * NPRI * 2) confs = (const float*)d_in[i];
    else if (in_sizes[i] == NPRI * 4) priors = (const float*)d_in[i];
  }
  float* out = (float*)d_out;   // f32: [B,K,5] dets ++ [B,K] keep

  char* ws = (char*)d_ws;
  size_t off = 0;
  u64* keyG = (u64*)(ws + off);          off += (size_t)BATCH * NCH * KTOP * 8; // 11,010,048
  u64* midG = (u64*)(ws + off);          off += (size_t)BATCH * 3 * KTOP * 8;   //  1,572,864
  float* boxF = (float*)(ws + off);      off += (size_t)BATCH * KTOP * 4 * 4;   //  1,048,576
  float* scoreF = (float*)(ws + off);    off += (size_t)BATCH * KTOP * 4;       //    262,144
  u64* validW = (u64*)(ws + off);        off += (size_t)BATCH * 16 * 8;         //      8,192
  // total ~13.9 MB

  k_sort<<<BATCH * NCH, 256, 0, stream>>>(confs, keyG);
  k_merge7<<<BATCH * 3, 256, 0, stream>>>(keyG, midG);
  k_merge3<<<BATCH, 256, 0, stream>>>(midG, locs, priors, boxF, scoreF, validW);
  k_nms<<<BATCH, 256, 0, stream>>>(boxF, scoreF, validW, out);
}

// Round 19
// 308.981 us; speedup vs baseline: 1.7340x; 1.7340x over previous
//
#include <hip/hip_runtime.h>

#define NPRI 21504
#define BATCH 64
#define KTOP 1024
#define NCH 21

typedef unsigned long long u64;
typedef unsigned int u32;

// correctly-rounded f32 exp via f64 libm exp (validated: absmax 3e-8)
__device__ __forceinline__ float crexpf(float x) { return (float)exp((double)x); }

__device__ __forceinline__ u64 readlane64(u64 v, int lane) {
  int lo = __builtin_amdgcn_readlane((int)(u32)v, lane);
  int hi = __builtin_amdgcn_readlane((int)(u32)(v >> 32), lane);
  return ((u64)(u32)hi << 32) | (u64)(u32)lo;
}

// Key packing (validated): key = (score_bits<<15) | (NPRI-1-idx). Unique keys;
// desc u64 order == (score desc, idx asc) == lax.top_k stable order => any
// correct top-1024 structure is bit-exact.

// K1: fused score + per-chunk bitonic sort (r12-validated, 1344 blocks, 8 KB).
__global__ __launch_bounds__(256) void k_sort(const float* __restrict__ confs,
                                              u64* __restrict__ keyG) {
  const int b = blockIdx.x / NCH;
  const int c = blockIdx.x % NCH;
  __shared__ u64 ks[KTOP];
  const float2* cf = (const float2*)confs + (size_t)b * NPRI + c * KTOP;
  for (int i = threadIdx.x; i < KTOP; i += 256) {
    float2 v = cf[i];
    float m = fmaxf(v.x, v.y);
    float e0 = crexpf(v.x - m);
    float e1 = crexpf(v.y - m);
    float s = e1 / (e0 + e1);          // exact f32 steps (validated)
    int idx = c * KTOP + i;
    ks[i] = ((u64)__float_as_uint(s) << 15) | (u64)(NPRI - 1 - idx);
  }
  for (int k = 2; k <= KTOP; k <<= 1) {
    for (int j = k >> 1; j > 0; j >>= 1) {
      __syncthreads();
      for (int l = threadIdx.x; l < KTOP; l += 256) {
        int p = l ^ j;
        if (p > l) {
          u64 a = ks[l], q = ks[p];
          bool up = ((l & k) == 0);
          if ((a > q) != up) { ks[l] = q; ks[p] = a; }
        }
      }
    }
  }
  __syncthreads();
  u64* dst = keyG + (size_t)b * NPRI + (size_t)c * KTOP;
  for (int i = threadIdx.x; i < KTOP; i += 256) dst[i] = ks[i];
}

// K2: 3 blocks/image: serially merge 7 runs -> top-1024 (r17-validated).
__global__ __launch_bounds__(256) void k_merge7(const u64* __restrict__ keyG,
                                                u64* __restrict__ midG) {
  const int b = blockIdx.x / 3;
  const int p3 = blockIdx.x % 3;
  __shared__ u64 A[KTOP];
  __shared__ u64 Bv[KTOP];
  const u64* src = keyG + ((size_t)b * NCH + p3 * 7) * KTOP;
  for (int i = threadIdx.x; i < KTOP; i += 256) A[i] = src[i];
  for (int c = 1; c < 7; c++) {
    __syncthreads();
    for (int i = threadIdx.x; i < KTOP; i += 256)
      Bv[i] = src[(size_t)c * KTOP + (KTOP - 1 - i)];   // reversed: asc
    __syncthreads();
    for (int i = threadIdx.x; i < KTOP; i += 256)
      if (Bv[i] > A[i]) A[i] = Bv[i];                    // half-cleaner
    for (int j = KTOP / 2; j > 0; j >>= 1) {             // clean -> desc
      __syncthreads();
      for (int l = threadIdx.x; l < KTOP; l += 256) {
        int p = l ^ j;
        if (p > l) {
          u64 a = A[l], q = A[p];
          if (a < q) { A[l] = q; A[p] = a; }
        }
      }
    }
  }
  __syncthreads();
  u64* d = midG + ((size_t)b * 3 + p3) * KTOP;
  for (int i = threadIdx.x; i < KTOP; i += 256) d[i] = A[i];
}

// K3: per image: merge 3 mids -> top-1024, then validated decode + valid-ballot.
__global__ __launch_bounds__(256) void k_merge3(const u64* __restrict__ midG,
                                                const float* __restrict__ locs,
                                                const float* __restrict__ priors,
                                                float* __restrict__ boxF,
                                                float* __restrict__ scoreF,
                                                u64* __restrict__ validW) {
  const int b = blockIdx.x;
  const int t = threadIdx.x;
  __shared__ u64 A[KTOP];
  __shared__ u64 Bv[KTOP];
  const u64* src = midG + (size_t)b * 3 * KTOP;
  for (int i = t; i < KTOP; i += 256) A[i] = src[i];
  for (int c = 1; c < 3; c++) {
    __syncthreads();
    for (int i = t; i < KTOP; i += 256)
      Bv[i] = src[(size_t)c * KTOP + (KTOP - 1 - i)];
    __syncthreads();
    for (int i = t; i < KTOP; i += 256)
      if (Bv[i] > A[i]) A[i] = Bv[i];
    for (int j = KTOP / 2; j > 0; j >>= 1) {
      __syncthreads();
      for (int l = t; l < KTOP; l += 256) {
        int p = l ^ j;
        if (p > l) {
          u64 a = A[l], q = A[p];
          if (a < q) { A[l] = q; A[p] = a; }
        }
      }
    }
  }
  __syncthreads();
  // decode top-1024: f32-stepwise (identical expressions to validated round 7)
  for (int i = t; i < KTOP; i += 256) {
    u64 K = A[i];
    float sv = __uint_as_float((u32)(K >> 15));
    int idx = NPRI - 1 - (int)(K & 0x7FFFu);
    float4 lo = ((const float4*)locs)[(size_t)b * NPRI + idx];
    float4 pr = ((const float4*)priors)[idx];
    float cx = pr.x + (lo.x * 0.1f) * pr.z;
    float cy = pr.y + (lo.y * 0.1f) * pr.w;
    float w  = pr.z * crexpf(lo.z * 0.2f);
    float h  = pr.w * crexpf(lo.w * 0.2f);
    float x1 = cx - w * 0.5f;
    float y1 = cy - h * 0.5f;
    float x2 = x1 + w;
    float y2 = y1 + h;
    size_t o = (size_t)b * KTOP + i;
    boxF[o * 4 + 0] = x1;
    boxF[o * 4 + 1] = y1;
    boxF[o * 4 + 2] = x2;
    boxF[o * 4 + 3] = y2;
    scoreF[o] = sv;
    u64 mask = __ballot(sv > 0.5f);       // wave covers group i>>6
    if ((t & 63) == 0) validW[(size_t)b * 16 + (i >> 6)] = mask;
  }
}

// K4: upper-triangle suppression bitmask, balanced 40-task mapping
// (r13/r17-validated). Same IoU bits; diag words (w==g) now go to supD
// (contiguous [b][g][64]) so k_scan's chain never waits on global loads.
__global__ __launch_bounds__(256) void k_iou(const float* __restrict__ boxF,
                                             u64* __restrict__ supF,
                                             u64* __restrict__ supD) {
  const int b = blockIdx.y;
  int task = blockIdx.x;               // 0..39
  int g = 0, base = 0;
  for (int gg = 0; gg < 16; gg++) {
    int cg = (16 - gg + 3) >> 2;
    if (task < base + cg) { g = gg; break; }
    base += cg;
  }
  const int c = task - base;
  const int w0 = g + 4 * c;            // first word of this chunk
  __shared__ float4 BXS[256];
  __shared__ float ARS[256];
  const float4* bb = (const float4*)(boxF + (size_t)b * KTOP * 4);
  {
    int j = w0 * 64 + threadIdx.x;
    if (j < KTOP) {
      float4 v = bb[j];
      BXS[threadIdx.x] = v;
      ARS[threadIdx.x] = fmaxf(v.z - v.x, 0.0f) * fmaxf(v.w - v.y, 0.0f);
    }
  }
  const int r = threadIdx.x & 63;
  const int v = threadIdx.x >> 6;      // wave 0..3
  const int i = g * 64 + r;
  float4 bi = bb[i];
  float a = fmaxf(bi.z - bi.x, 0.0f) * fmaxf(bi.w - bi.y, 0.0f);
  __syncthreads();
  const int w = w0 + v;
  if (w < 16) {
    u64 word = 0;
    const int lbase = v * 64;
    for (int jb = 0; jb < 64; jb++) {
      int lj = lbase + jb;
      float4 bj = BXS[lj];             // broadcast (w uniform in wave)
      float aj = ARS[lj];
      float lx = fmaxf(bi.x, bj.x);
      float ly = fmaxf(bi.y, bj.y);
      float rx = fminf(bi.z, bj.z);
      float ry = fminf(bi.w, bj.w);
      float iw = fmaxf(rx - lx, 0.0f);
      float ih = fmaxf(ry - ly, 0.0f);
      float inter = iw * ih;
      float uni = (a + aj) - inter;
      float iou = inter / fmaxf(uni, 1e-9f);
      if (iou > 0.4f) word |= (1ULL << jb);
    }
    if (w == g) {
      word &= (r == 63) ? 0ULL : (~0ULL << (r + 1));   // j > i
      supD[((size_t)b * 16 + g) * 64 + r] = word;
    } else {
      supF[((size_t)b * KTOP + i) * 16 + w] = word;
    }
  }
}

// K5: greedy scan v3. All diag words preloaded to LDS once (chain never waits
// on global); lane0 records kept indices during the r12-validated ctz chain;
// OR step loads ONLY kept rows' future words (parallel, one L2 round-trip).
__global__ __launch_bounds__(256) void k_scan(const u64* __restrict__ supF,
                                              const u64* __restrict__ supD,
                                              const u64* __restrict__ validW,
                                              const float* __restrict__ boxF,
                                              const float* __restrict__ scoreF,
                                              float* __restrict__ out) {
  const int b = blockIdx.x;
  const int t = threadIdx.x;
  const int lane = t & 63;
  __shared__ u64 diagL[16][64];        // 8 KB: all intra-group words
  __shared__ u64 keepW[16], vW[16];
  __shared__ u32 remvLo[16], remvHi[16];
  __shared__ int kidx[64];
  __shared__ int kcnt;
  for (int l = t; l < 1024; l += 256)
    diagL[l >> 6][l & 63] = supD[(size_t)b * 1024 + l];
  if (t < 16) { remvLo[t] = 0; remvHi[t] = 0; vW[t] = validW[(size_t)b * 16 + t]; }
  __syncthreads();
  for (int g = 0; g < 16; g++) {
    if (t < 64) {
      u64 diag = diagL[g][lane];
      u64 remv = ((u64)remvHi[g] << 32) | (u64)remvLo[g];
      u64 alive = vW[g] & ~remv;         // wave-uniform
      u64 keep = 0, m = alive;
      int kc = 0;
      while (m) {
        int i = __builtin_ctzll(m);
        keep |= (1ULL << i);
        if (lane == 0) kidx[kc] = i;
        kc++;
        alive &= ~readlane64(diag, i);   // row i has only bits j>i
        m = (i == 63) ? 0ULL : (alive & (~0ULL << (i + 1)));
      }
      if (lane == 0) { keepW[g] = keep; kcnt = kc; }
    }
    __syncthreads();
    // OR kept rows' future words into remv (parallel global loads, disjoint-ish)
    {
      const int nw = 15 - g;
      const int nt = kcnt * nw;
      for (int task = t; task < nt; task += 256) {
        int ki = task / nw;
        int w = g + 1 + (task - ki * nw);
        int i = g * 64 + kidx[ki];
        u64 r = supF[((size_t)b * KTOP + i) * 16 + w];
        if (r) {
          u32 rl = (u32)r, rh = (u32)(r >> 32);
          if (rl) atomicOr(&remvLo[w], rl);
          if (rh) atomicOr(&remvHi[w], rh);
        }
      }
    }
    __syncthreads();   // remv visible for next group's chain
  }
  const float* bb = boxF + (size_t)b * KTOP * 4;
  const float* sc = scoreF + (size_t)b * KTOP;
  for (int i = t; i < KTOP; i += 256) {
    float kf = ((keepW[i >> 6] >> (i & 63)) & 1ULL) ? 1.0f : 0.0f;
    size_t o5 = ((size_t)b * KTOP + i) * 5;
    out[o5 + 0] = bb[i * 4 + 0] * kf;
    out[o5 + 1] = bb[i * 4 + 1] * kf;
    out[o5 + 2] = bb[i * 4 + 2] * kf;
    out[o5 + 3] = bb[i * 4 + 3] * kf;
    out[o5 + 4] = sc[i] * kf;
    out[(size_t)BATCH * KTOP * 5 + (size_t)b * KTOP + i] = kf;
  }
}

extern "C" void kernel_launch(void* const* d_in, const int* in_sizes, int n_in,
                              void* d_out, int out_size, void* d_ws, size_t ws_size,
                              hipStream_t stream) {
  const float* locs = nullptr;
  const float* confs = nullptr;
  const float* priors = nullptr;
  for (int i = 0; i < n_in; i++) {
    if (in_sizes[i] == BATCH * NPRI * 4) locs = (const float*)d_in[i];
    else if (in_sizes[i] == BATCH * NPRI * 2) confs = (const float*)d_in[i];
    else if (in_sizes[i] == NPRI * 4) priors = (const float*)d_in[i];
  }
  float* out = (float*)d_out;   // f32: [B,K,5] dets ++ [B,K] keep

  char* ws = (char*)d_ws;
  size_t off = 0;
  u64* keyG = (u64*)(ws + off);          // B*21*1024*8 = 11,010,048
  u64* supF = (u64*)(ws + off);          // alias: keyG dead after k_merge7 (8,388,608)
  off += (size_t)BATCH * NCH * KTOP * 8;
  u64* midG = (u64*)(ws + off);          off += (size_t)BATCH * 3 * KTOP * 8;   // 1,572,864
  float* boxF = (float*)(ws + off);      off += (size_t)BATCH * KTOP * 4 * 4;   // 1,048,576
  float* scoreF = (float*)(ws + off);    off += (size_t)BATCH * KTOP * 4;       //   262,144
  u64* validW = (u64*)(ws + off);        off += (size_t)BATCH * 16 * 8;         //     8,192
  u64* supD = (u64*)(ws + off);          off += (size_t)BATCH * 16 * 64 * 8;    //   524,288
  // total ~14.4 MB

  k_sort<<<BATCH * NCH, 256, 0, stream>>>(confs, keyG);
  k_merge7<<<BATCH * 3, 256, 0, stream>>>(keyG, midG);
  k_merge3<<<BATCH, 256, 0, stream>>>(midG, locs, priors, boxF, scoreF, validW);
  k_iou<<<dim3(40, BATCH), 256, 0, stream>>>(boxF, supF, supD);
  k_scan<<<BATCH, 256, 0, stream>>>(supF, supD, validW, boxF, scoreF, out);
}

// Round 20
// 285.449 us; speedup vs baseline: 1.8770x; 1.0824x over previous
//
#include <hip/hip_runtime.h>

#define NPRI 21504
#define BATCH 64
#define KTOP 1024
#define NCH 21

typedef unsigned long long u64;
typedef unsigned int u32;

// correctly-rounded f32 exp via f64 libm exp (validated: absmax 3e-8)
__device__ __forceinline__ float crexpf(float x) { return (float)exp((double)x); }

__device__ __forceinline__ u64 readlane64(u64 v, int lane) {
  int lo = __builtin_amdgcn_readlane((int)(u32)v, lane);
  int hi = __builtin_amdgcn_readlane((int)(u32)(v >> 32), lane);
  return ((u64)(u32)hi << 32) | (u64)(u32)lo;
}

// Key packing (validated): key = (score_bits<<15) | (NPRI-1-idx). Unique keys;
// desc u64 order == (score desc, idx asc) == lax.top_k stable order => any
// correct top-1024 structure is bit-exact.

// K1: fused score + per-chunk bitonic sort (r12-validated, 1344 blocks, 8 KB).
__global__ __launch_bounds__(256) void k_sort(const float* __restrict__ confs,
                                              u64* __restrict__ keyG) {
  const int b = blockIdx.x / NCH;
  const int c = blockIdx.x % NCH;
  __shared__ u64 ks[KTOP];
  const float2* cf = (const float2*)confs + (size_t)b * NPRI + c * KTOP;
  for (int i = threadIdx.x; i < KTOP; i += 256) {
    float2 v = cf[i];
    float m = fmaxf(v.x, v.y);
    float e0 = crexpf(v.x - m);
    float e1 = crexpf(v.y - m);
    float s = e1 / (e0 + e1);          // exact f32 steps (validated)
    int idx = c * KTOP + i;
    ks[i] = ((u64)__float_as_uint(s) << 15) | (u64)(NPRI - 1 - idx);
  }
  for (int k = 2; k <= KTOP; k <<= 1) {
    for (int j = k >> 1; j > 0; j >>= 1) {
      __syncthreads();
      for (int l = threadIdx.x; l < KTOP; l += 256) {
        int p = l ^ j;
        if (p > l) {
          u64 a = ks[l], q = ks[p];
          bool up = ((l & k) == 0);
          if ((a > q) != up) { ks[l] = q; ks[p] = a; }
        }
      }
    }
  }
  __syncthreads();
  u64* dst = keyG + (size_t)b * NPRI + (size_t)c * KTOP;
  for (int i = threadIdx.x; i < KTOP; i += 256) dst[i] = ks[i];
}

// K2: 3 blocks/image: serially merge 7 runs -> top-1024 (r17-validated).
__global__ __launch_bounds__(256) void k_merge7(const u64* __restrict__ keyG,
                                                u64* __restrict__ midG) {
  const int b = blockIdx.x / 3;
  const int p3 = blockIdx.x % 3;
  __shared__ u64 A[KTOP];
  __shared__ u64 Bv[KTOP];
  const u64* src = keyG + ((size_t)b * NCH + p3 * 7) * KTOP;
  for (int i = threadIdx.x; i < KTOP; i += 256) A[i] = src[i];
  for (int c = 1; c < 7; c++) {
    __syncthreads();
    for (int i = threadIdx.x; i < KTOP; i += 256)
      Bv[i] = src[(size_t)c * KTOP + (KTOP - 1 - i)];   // reversed: asc
    __syncthreads();
    for (int i = threadIdx.x; i < KTOP; i += 256)
      if (Bv[i] > A[i]) A[i] = Bv[i];                    // half-cleaner
    for (int j = KTOP / 2; j > 0; j >>= 1) {             // clean -> desc
      __syncthreads();
      for (int l = threadIdx.x; l < KTOP; l += 256) {
        int p = l ^ j;
        if (p > l) {
          u64 a = A[l], q = A[p];
          if (a < q) { A[l] = q; A[p] = a; }
        }
      }
    }
  }
  __syncthreads();
  u64* d = midG + ((size_t)b * 3 + p3) * KTOP;
  for (int i = threadIdx.x; i < KTOP; i += 256) d[i] = A[i];
}

// K3: per image: merge 3 mids -> top-1024, then validated decode + valid-ballot.
__global__ __launch_bounds__(256) void k_merge3(const u64* __restrict__ midG,
                                                const float* __restrict__ locs,
                                                const float* __restrict__ priors,
                                                float* __restrict__ boxF,
                                                float* __restrict__ scoreF,
                                                u64* __restrict__ validW) {
  const int b = blockIdx.x;
  const int t = threadIdx.x;
  __shared__ u64 A[KTOP];
  __shared__ u64 Bv[KTOP];
  const u64* src = midG + (size_t)b * 3 * KTOP;
  for (int i = t; i < KTOP; i += 256) A[i] = src[i];
  for (int c = 1; c < 3; c++) {
    __syncthreads();
    for (int i = t; i < KTOP; i += 256)
      Bv[i] = src[(size_t)c * KTOP + (KTOP - 1 - i)];
    __syncthreads();
    for (int i = t; i < KTOP; i += 256)
      if (Bv[i] > A[i]) A[i] = Bv[i];
    for (int j = KTOP / 2; j > 0; j >>= 1) {
      __syncthreads();
      for (int l = t; l < KTOP; l += 256) {
        int p = l ^ j;
        if (p > l) {
          u64 a = A[l], q = A[p];
          if (a < q) { A[l] = q; A[p] = a; }
        }
      }
    }
  }
  __syncthreads();
  // decode top-1024: f32-stepwise (identical expressions to validated round 7)
  for (int i = t; i < KTOP; i += 256) {
    u64 K = A[i];
    float sv = __uint_as_float((u32)(K >> 15));
    int idx = NPRI - 1 - (int)(K & 0x7FFFu);
    float4 lo = ((const float4*)locs)[(size_t)b * NPRI + idx];
    float4 pr = ((const float4*)priors)[idx];
    float cx = pr.x + (lo.x * 0.1f) * pr.z;
    float cy = pr.y + (lo.y * 0.1f) * pr.w;
    float w  = pr.z * crexpf(lo.z * 0.2f);
    float h  = pr.w * crexpf(lo.w * 0.2f);
    float x1 = cx - w * 0.5f;
    float y1 = cy - h * 0.5f;
    float x2 = x1 + w;
    float y2 = y1 + h;
    size_t o = (size_t)b * KTOP + i;
    boxF[o * 4 + 0] = x1;
    boxF[o * 4 + 1] = y1;
    boxF[o * 4 + 2] = x2;
    boxF[o * 4 + 3] = y2;
    scoreF[o] = sv;
    u64 mask = __ballot(sv > 0.5f);       // wave covers group i>>6
    if ((t & 63) == 0) validW[(size_t)b * 16 + (i >> 6)] = mask;
  }
}

// K4: upper-triangle suppression bitmask, balanced 40-task mapping
// (r13/r17-validated verbatim). Words w<g never written nor read.
__global__ __launch_bounds__(256) void k_iou(const float* __restrict__ boxF,
                                             u64* __restrict__ sup) {
  const int b = blockIdx.y;
  int task = blockIdx.x;               // 0..39
  int g = 0, base = 0;
  for (int gg = 0; gg < 16; gg++) {
    int cg = (16 - gg + 3) >> 2;
    if (task < base + cg) { g = gg; break; }
    base += cg;
  }
  const int c = task - base;
  const int w0 = g + 4 * c;            // first word of this chunk
  __shared__ float4 BXS[256];
  __shared__ float ARS[256];
  const float4* bb = (const float4*)(boxF + (size_t)b * KTOP * 4);
  {
    int j = w0 * 64 + threadIdx.x;
    if (j < KTOP) {
      float4 v = bb[j];
      BXS[threadIdx.x] = v;
      ARS[threadIdx.x] = fmaxf(v.z - v.x, 0.0f) * fmaxf(v.w - v.y, 0.0f);
    }
  }
  const int r = threadIdx.x & 63;
  const int v = threadIdx.x >> 6;      // wave 0..3
  const int i = g * 64 + r;
  float4 bi = bb[i];
  float a = fmaxf(bi.z - bi.x, 0.0f) * fmaxf(bi.w - bi.y, 0.0f);
  __syncthreads();
  const int w = w0 + v;
  if (w < 16) {
    u64 word = 0;
    const int lbase = v * 64;
    for (int jb = 0; jb < 64; jb++) {
      int lj = lbase + jb;
      float4 bj = BXS[lj];             // broadcast (w uniform in wave)
      float aj = ARS[lj];
      float lx = fmaxf(bi.x, bj.x);
      float ly = fmaxf(bi.y, bj.y);
      float rx = fminf(bi.z, bj.z);
      float ry = fminf(bi.w, bj.w);
      float iw = fmaxf(rx - lx, 0.0f);
      float ih = fmaxf(ry - ly, 0.0f);
      float inter = iw * ih;
      float uni = (a + aj) - inter;
      float iou = inter / fmaxf(uni, 1e-9f);
      if (iou > 0.4f) word |= (1ULL << jb);
    }
    if (w == g) word &= (r == 63) ? 0ULL : (~0ULL << (r + 1));   // j > i
    sup[((size_t)b * KTOP + i) * 16 + w] = word;
  }
}

// K5: greedy scan v4 — ALL of this image's sup matrix bulk-loaded to LDS
// (128 KB dynamic, launch-time size) BEFORE the serial loop: chain (r12-
// validated ctz+readlane) and dense OR run with zero global access.
__global__ __launch_bounds__(256) void k_scan(const u64* __restrict__ sup,
                                              const u64* __restrict__ validW,
                                              const float* __restrict__ boxF,
                                              const float* __restrict__ scoreF,
                                              float* __restrict__ out) {
  extern __shared__ u64 rows[];        // [1024][16] = 131072 B
  const int b = blockIdx.x;
  const int t = threadIdx.x;
  const int lane = t & 63;
  __shared__ u64 keepW[16], vW[16], remv[16];
  const u64* supB = sup + (size_t)b * KTOP * 16;
  for (int l = t; l < KTOP * 16; l += 256) rows[l] = supB[l];   // bulk, coalesced
  if (t < 16) { remv[t] = 0; vW[t] = validW[(size_t)b * 16 + t]; }
  __syncthreads();
  for (int g = 0; g < 16; g++) {
    if (t < 64) {
      u64 diag = rows[(g * 64 + lane) * 16 + g];   // intra-group word (LDS)
      u64 alive = vW[g] & ~remv[g];                // wave-uniform
      u64 keep = 0, m = alive;
      while (m) {
        int i = __builtin_ctzll(m);
        keep |= (1ULL << i);
        alive &= ~readlane64(diag, i);             // row i has only bits j>i
        m = (i == 63) ? 0ULL : (alive & (~0ULL << (i + 1)));
      }
      if (lane == 0) keepW[g] = keep;
    }
    __syncthreads();
    // OR kept rows into removal words of future groups (pure LDS)
    {
      u64 kw = keepW[g];
      int w = t & 15;
      if (w > g) {
        int i0 = (t >> 4) * 4;
        u64 acc = 0;
        for (int i = i0; i < i0 + 4; i++)
          if ((kw >> i) & 1ULL) acc |= rows[(g * 64 + i) * 16 + w];
        if (acc) atomicOr(&remv[w], acc);
      }
    }
    __syncthreads();   // remv visible for next group's chain
  }
  const float* bb = boxF + (size_t)b * KTOP * 4;
  const float* sc = scoreF + (size_t)b * KTOP;
  for (int i = t; i < KTOP; i += 256) {
    float kf = ((keepW[i >> 6] >> (i & 63)) & 1ULL) ? 1.0f : 0.0f;
    size_t o5 = ((size_t)b * KTOP + i) * 5;
    out[o5 + 0] = bb[i * 4 + 0] * kf;
    out[o5 + 1] = bb[i * 4 + 1] * kf;
    out[o5 + 2] = bb[i * 4 + 2] * kf;
    out[o5 + 3] = bb[i * 4 + 3] * kf;
    out[o5 + 4] = sc[i] * kf;
    out[(size_t)BATCH * KTOP * 5 + (size_t)b * KTOP + i] = kf;
  }
}

extern "C" void kernel_launch(void* const* d_in, const int* in_sizes, int n_in,
                              void* d_out, int out_size, void* d_ws, size_t ws_size,
                              hipStream_t stream) {
  const float* locs = nullptr;
  const float* confs = nullptr;
  const float* priors = nullptr;
  for (int i = 0; i < n_in; i++) {
    if (in_sizes[i] == BATCH * NPRI * 4) locs = (const float*)d_in[i];
    else if (in_sizes[i] == BATCH * NPRI * 2) confs = (const float*)d_in[i];
    else if (in_sizes[i] == NPRI * 4) priors = (const float*)d_in[i];
  }
  float* out = (float*)d_out;   // f32: [B,K,5] dets ++ [B,K] keep

  char* ws = (char*)d_ws;
  size_t off = 0;
  u64* keyG = (u64*)(ws + off);          // B*21*1024*8 = 11,010,048
  u64* sup = (u64*)(ws + off);           // alias: keyG dead after k_merge7 (8,388,608)
  off += (size_t)BATCH * NCH * KTOP * 8;
  u64* midG = (u64*)(ws + off);          off += (size_t)BATCH * 3 * KTOP * 8;   // 1,572,864
  float* boxF = (float*)(ws + off);      off += (size_t)BATCH * KTOP * 4 * 4;   // 1,048,576
  float* scoreF = (float*)(ws + off);    off += (size_t)BATCH * KTOP * 4;       //   262,144
  u64* validW = (u64*)(ws + off);        off += (size_t)BATCH * 16 * 8;         //     8,192
  // total ~13.9 MB

  k_sort<<<BATCH * NCH, 256, 0, stream>>>(confs, keyG);
  k_merge7<<<BATCH * 3, 256, 0, stream>>>(keyG, midG);
  k_merge3<<<BATCH, 256, 0, stream>>>(midG, locs, priors, boxF, scoreF, validW);
  k_iou<<<dim3(40, BATCH), 256, 0, stream>>>(boxF, sup);
  k_scan<<<BATCH, 256, 131072, stream>>>(sup, validW, boxF, scoreF, out);
}

// Round 21
// 271.091 us; speedup vs baseline: 1.9764x; 1.0530x over previous
//
#include <hip/hip_runtime.h>

#define NPRI 21504
#define BATCH 64
#define KTOP 1024
#define NCH 21

typedef unsigned long long u64;
typedef unsigned int u32;

// correctly-rounded f32 exp via f64 libm exp (validated: absmax 3e-8)
__device__ __forceinline__ float crexpf(float x) { return (float)exp((double)x); }

__device__ __forceinline__ u64 readlane64(u64 v, int lane) {
  int lo = __builtin_amdgcn_readlane((int)(u32)v, lane);
  int hi = __builtin_amdgcn_readlane((int)(u32)(v >> 32), lane);
  return ((u64)(u32)hi << 32) | (u64)(u32)lo;
}

// Key packing (validated): key = (score_bits<<15) | (NPRI-1-idx). Unique keys;
// desc u64 order == (score desc, idx asc) == lax.top_k stable order => any
// correct top-1024 structure is bit-exact.

// K1: fused score + per-chunk bitonic sort (r12-validated, 1344 blocks, 8 KB).
__global__ __launch_bounds__(256) void k_sort(const float* __restrict__ confs,
                                              u64* __restrict__ keyG) {
  const int b = blockIdx.x / NCH;
  const int c = blockIdx.x % NCH;
  __shared__ u64 ks[KTOP];
  const float2* cf = (const float2*)confs + (size_t)b * NPRI + c * KTOP;
  for (int i = threadIdx.x; i < KTOP; i += 256) {
    float2 v = cf[i];
    float m = fmaxf(v.x, v.y);
    float e0 = crexpf(v.x - m);
    float e1 = crexpf(v.y - m);
    float s = e1 / (e0 + e1);          // exact f32 steps (validated)
    int idx = c * KTOP + i;
    ks[i] = ((u64)__float_as_uint(s) << 15) | (u64)(NPRI - 1 - idx);
  }
  for (int k = 2; k <= KTOP; k <<= 1) {
    for (int j = k >> 1; j > 0; j >>= 1) {
      __syncthreads();
      for (int l = threadIdx.x; l < KTOP; l += 256) {
        int p = l ^ j;
        if (p > l) {
          u64 a = ks[l], q = ks[p];
          bool up = ((l & k) == 0);
          if ((a > q) != up) { ks[l] = q; ks[p] = a; }
        }
      }
    }
  }
  __syncthreads();
  u64* dst = keyG + (size_t)b * NPRI + (size_t)c * KTOP;
  for (int i = threadIdx.x; i < KTOP; i += 256) dst[i] = ks[i];
}

// K2: 3 blocks/image: serially merge 7 runs -> top-1024 (r17-validated).
__global__ __launch_bounds__(256) void k_merge7(const u64* __restrict__ keyG,
                                                u64* __restrict__ midG) {
  const int b = blockIdx.x / 3;
  const int p3 = blockIdx.x % 3;
  __shared__ u64 A[KTOP];
  __shared__ u64 Bv[KTOP];
  const u64* src = keyG + ((size_t)b * NCH + p3 * 7) * KTOP;
  for (int i = threadIdx.x; i < KTOP; i += 256) A[i] = src[i];
  for (int c = 1; c < 7; c++) {
    __syncthreads();
    for (int i = threadIdx.x; i < KTOP; i += 256)
      Bv[i] = src[(size_t)c * KTOP + (KTOP - 1 - i)];   // reversed: asc
    __syncthreads();
    for (int i = threadIdx.x; i < KTOP; i += 256)
      if (Bv[i] > A[i]) A[i] = Bv[i];                    // half-cleaner
    for (int j = KTOP / 2; j > 0; j >>= 1) {             // clean -> desc
      __syncthreads();
      for (int l = threadIdx.x; l < KTOP; l += 256) {
        int p = l ^ j;
        if (p > l) {
          u64 a = A[l], q = A[p];
          if (a < q) { A[l] = q; A[p] = a; }
        }
      }
    }
  }
  __syncthreads();
  u64* d = midG + ((size_t)b * 3 + p3) * KTOP;
  for (int i = threadIdx.x; i < KTOP; i += 256) d[i] = A[i];
}

// K3: per image: merge 3 mids -> top-1024, then validated decode + valid-ballot.
__global__ __launch_bounds__(256) void k_merge3(const u64* __restrict__ midG,
                                                const float* __restrict__ locs,
                                                const float* __restrict__ priors,
                                                float* __restrict__ boxF,
                                                float* __restrict__ scoreF,
                                                u64* __restrict__ validW) {
  const int b = blockIdx.x;
  const int t = threadIdx.x;
  __shared__ u64 A[KTOP];
  __shared__ u64 Bv[KTOP];
  const u64* src = midG + (size_t)b * 3 * KTOP;
  for (int i = t; i < KTOP; i += 256) A[i] = src[i];
  for (int c = 1; c < 3; c++) {
    __syncthreads();
    for (int i = t; i < KTOP; i += 256)
      Bv[i] = src[(size_t)c * KTOP + (KTOP - 1 - i)];
    __syncthreads();
    for (int i = t; i < KTOP; i += 256)
      if (Bv[i] > A[i]) A[i] = Bv[i];
    for (int j = KTOP / 2; j > 0; j >>= 1) {
      __syncthreads();
      for (int l = t; l < KTOP; l += 256) {
        int p = l ^ j;
        if (p > l) {
          u64 a = A[l], q = A[p];
          if (a < q) { A[l] = q; A[p] = a; }
        }
      }
    }
  }
  __syncthreads();
  // decode top-1024: f32-stepwise (identical expressions to validated round 7)
  for (int i = t; i < KTOP; i += 256) {
    u64 K = A[i];
    float sv = __uint_as_float((u32)(K >> 15));
    int idx = NPRI - 1 - (int)(K & 0x7FFFu);
    float4 lo = ((const float4*)locs)[(size_t)b * NPRI + idx];
    float4 pr = ((const float4*)priors)[idx];
    float cx = pr.x + (lo.x * 0.1f) * pr.z;
    float cy = pr.y + (lo.y * 0.1f) * pr.w;
    float w  = pr.z * crexpf(lo.z * 0.2f);
    float h  = pr.w * crexpf(lo.w * 0.2f);
    float x1 = cx - w * 0.5f;
    float y1 = cy - h * 0.5f;
    float x2 = x1 + w;
    float y2 = y1 + h;
    size_t o = (size_t)b * KTOP + i;
    boxF[o * 4 + 0] = x1;
    boxF[o * 4 + 1] = y1;
    boxF[o * 4 + 2] = x2;
    boxF[o * 4 + 3] = y2;
    scoreF[o] = sv;
    u64 mask = __ballot(sv > 0.5f);       // wave covers group i>>6
    if ((t & 63) == 0) validW[(size_t)b * 16 + (i >> 6)] = mask;
  }
}

// K4: upper-triangle suppression bitmask, balanced 40-task mapping
// (r13/r17-validated verbatim). Words w<g never written nor read.
__global__ __launch_bounds__(256) void k_iou(const float* __restrict__ boxF,
                                             u64* __restrict__ sup) {
  const int b = blockIdx.y;
  int task = blockIdx.x;               // 0..39
  int g = 0, base = 0;
  for (int gg = 0; gg < 16; gg++) {
    int cg = (16 - gg + 3) >> 2;
    if (task < base + cg) { g = gg; break; }
    base += cg;
  }
  const int c = task - base;
  const int w0 = g + 4 * c;            // first word of this chunk
  __shared__ float4 BXS[256];
  __shared__ float ARS[256];
  const float4* bb = (const float4*)(boxF + (size_t)b * KTOP * 4);
  {
    int j = w0 * 64 + threadIdx.x;
    if (j < KTOP) {
      float4 v = bb[j];
      BXS[threadIdx.x] = v;
      ARS[threadIdx.x] = fmaxf(v.z - v.x, 0.0f) * fmaxf(v.w - v.y, 0.0f);
    }
  }
  const int r = threadIdx.x & 63;
  const int v = threadIdx.x >> 6;      // wave 0..3
  const int i = g * 64 + r;
  float4 bi = bb[i];
  float a = fmaxf(bi.z - bi.x, 0.0f) * fmaxf(bi.w - bi.y, 0.0f);
  __syncthreads();
  const int w = w0 + v;
  if (w < 16) {
    u64 word = 0;
    const int lbase = v * 64;
    for (int jb = 0; jb < 64; jb++) {
      int lj = lbase + jb;
      float4 bj = BXS[lj];             // broadcast (w uniform in wave)
      float aj = ARS[lj];
      float lx = fmaxf(bi.x, bj.x);
      float ly = fmaxf(bi.y, bj.y);
      float rx = fminf(bi.z, bj.z);
      float ry = fminf(bi.w, bj.w);
      float iw = fmaxf(rx - lx, 0.0f);
      float ih = fmaxf(ry - ly, 0.0f);
      float inter = iw * ih;
      float uni = (a + aj) - inter;
      float iou = inter / fmaxf(uni, 1e-9f);
      if (iou > 0.4f) word |= (1ULL << jb);
    }
    if (w == g) word &= (r == 63) ? 0ULL : (~0ULL << (r + 1));   // j > i
    sup[((size_t)b * KTOP + i) * 16 + w] = word;
  }
}

// K5: greedy scan v5 — all sup in LDS (v4), but staged via ASYNC direct-to-LDS
// DMA (global_load_lds width=16, gfx950-verified): wave v streams 1 KB chunks
// c = v, v+4, ... (wave-uniform LDS base + lane*16 — exactly the HW mapping).
// 32 async issues/wave, no VGPR round-trip; __syncthreads drains vmcnt.
// Chain + OR logic byte-identical to r12-validated version.
__global__ __launch_bounds__(256) void k_scan(const u64* __restrict__ sup,
                                              const u64* __restrict__ validW,
                                              const float* __restrict__ boxF,
                                              const float* __restrict__ scoreF,
                                              float* __restrict__ out) {
  extern __shared__ u64 rows[];        // [1024][16] = 131072 B
  const int b = blockIdx.x;
  const int t = threadIdx.x;
  const int lane = t & 63;
  const int wv = t >> 6;               // wave 0..3
  __shared__ u64 keepW[16], vW[16], remv[16];
  const u64* supB = sup + (size_t)b * KTOP * 16;
  // async bulk stage: 128 chunks x 1 KB
  {
    const unsigned char* gb = (const unsigned char*)supB;
    unsigned char* lb = (unsigned char*)rows;
    for (int c = wv; c < 128; c += 4) {
      int off = c << 10;
      __builtin_amdgcn_global_load_lds(
          (const __attribute__((address_space(1))) unsigned int*)(gb + off + lane * 16),
          (__attribute__((address_space(3))) unsigned int*)(lb + off),
          16, 0, 0);
    }
  }
  if (t < 16) { remv[t] = 0; vW[t] = validW[(size_t)b * 16 + t]; }
  __syncthreads();                     // drains vmcnt (m97-validated semantics)
  for (int g = 0; g < 16; g++) {
    if (t < 64) {
      u64 diag = rows[(g * 64 + lane) * 16 + g];   // intra-group word (LDS)
      u64 alive = vW[g] & ~remv[g];                // wave-uniform
      u64 keep = 0, m = alive;
      while (m) {
        int i = __builtin_ctzll(m);
        keep |= (1ULL << i);
        alive &= ~readlane64(diag, i);             // row i has only bits j>i
        m = (i == 63) ? 0ULL : (alive & (~0ULL << (i + 1)));
      }
      if (lane == 0) keepW[g] = keep;
    }
    __syncthreads();
    // OR kept rows into removal words of future groups (pure LDS)
    {
      u64 kw = keepW[g];
      int w = t & 15;
      if (w > g) {
        int i0 = (t >> 4) * 4;
        u64 acc = 0;
        for (int i = i0; i < i0 + 4; i++)
          if ((kw >> i) & 1ULL) acc |= rows[(g * 64 + i) * 16 + w];
        if (acc) atomicOr(&remv[w], acc);
      }
    }
    __syncthreads();   // remv visible for next group's chain
  }
  const float* bb = boxF + (size_t)b * KTOP * 4;
  const float* sc = scoreF + (size_t)b * KTOP;
  for (int i = t; i < KTOP; i += 256) {
    float kf = ((keepW[i >> 6] >> (i & 63)) & 1ULL) ? 1.0f : 0.0f;
    size_t o5 = ((size_t)b * KTOP + i) * 5;
    out[o5 + 0] = bb[i * 4 + 0] * kf;
    out[o5 + 1] = bb[i * 4 + 1] * kf;
    out[o5 + 2] = bb[i * 4 + 2] * kf;
    out[o5 + 3] = bb[i * 4 + 3] * kf;
    out[o5 + 4] = sc[i] * kf;
    out[(size_t)BATCH * KTOP * 5 + (size_t)b * KTOP + i] = kf;
  }
}

extern "C" void kernel_launch(void* const* d_in, const int* in_sizes, int n_in,
                              void* d_out, int out_size, void* d_ws, size_t ws_size,
                              hipStream_t stream) {
  const float* locs = nullptr;
  const float* confs = nullptr;
  const float* priors = nullptr;
  for (int i = 0; i < n_in; i++) {
    if (in_sizes[i] == BATCH * NPRI * 4) locs = (const float*)d_in[i];
    else if (in_sizes[i] == BATCH * NPRI * 2) confs = (const float*)d_in[i];
    else if (in_sizes[i] == NPRI * 4) priors = (const float*)d_in[i];
  }
  float* out = (float*)d_out;   // f32: [B,K,5] dets ++ [B,K] keep

  char* ws = (char*)d_ws;
  size_t off = 0;
  u64* keyG = (u64*)(ws + off);          // B*21*1024*8 = 11,010,048
  u64* sup = (u64*)(ws + off);           // alias: keyG dead after k_merge7 (8,388,608)
  off += (size_t)BATCH * NCH * KTOP * 8;
  u64* midG = (u64*)(ws + off);          off += (size_t)BATCH * 3 * KTOP * 8;   // 1,572,864
  float* boxF = (float*)(ws + off);      off += (size_t)BATCH * KTOP * 4 * 4;   // 1,048,576
  float* scoreF = (float*)(ws + off);    off += (size_t)BATCH * KTOP * 4;       //   262,144
  u64* validW = (u64*)(ws + off);        off += (size_t)BATCH * 16 * 8;         //     8,192
  // total ~13.9 MB

  k_sort<<<BATCH * NCH, 256, 0, stream>>>(confs, keyG);
  k_merge7<<<BATCH * 3, 256, 0, stream>>>(keyG, midG);
  k_merge3<<<BATCH, 256, 0, stream>>>(midG, locs, priors, boxF, scoreF, validW);
  k_iou<<<dim3(40, BATCH), 256, 0, stream>>>(boxF, sup);
  k_scan<<<BATCH, 256, 131072, stream>>>(sup, validW, boxF, scoreF, out);
}

// Round 22
// 265.310 us; speedup vs baseline: 2.0194x; 1.0218x over previous
//
#include <hip/hip_runtime.h>

#define NPRI 21504
#define BATCH 64
#define KTOP 1024
#define NCH 21
#define SUPW 8704   // packed upper-triangle words/image = 64 * sum(16-g) = 64*136

typedef unsigned long long u64;
typedef unsigned int u32;

// correctly-rounded f32 exp via f64 libm exp (validated: absmax 3e-8)
__device__ __forceinline__ float crexpf(float x) { return (float)exp((double)x); }

__device__ __forceinline__ u64 readlane64(u64 v, int lane) {
  int lo = __builtin_amdgcn_readlane((int)(u32)v, lane);
  int hi = __builtin_amdgcn_readlane((int)(u32)(v >> 32), lane);
  return ((u64)(u32)hi << 32) | (u64)(u32)lo;
}

// packed row base for group g: 64 * (16g - g(g-1)/2)
__device__ __forceinline__ int supBase(int g) {
  return 64 * (16 * g - (g * (g - 1)) / 2);
}

// Key packing (validated): key = (score_bits<<15) | (NPRI-1-idx). Unique keys;
// desc u64 order == (score desc, idx asc) == lax.top_k stable order => any
// correct top-1024 structure is bit-exact.

// K1: fused score + per-chunk bitonic sort (r12-validated, 1344 blocks, 8 KB).
__global__ __launch_bounds__(256) void k_sort(const float* __restrict__ confs,
                                              u64* __restrict__ keyG) {
  const int b = blockIdx.x / NCH;
  const int c = blockIdx.x % NCH;
  __shared__ u64 ks[KTOP];
  const float2* cf = (const float2*)confs + (size_t)b * NPRI + c * KTOP;
  for (int i = threadIdx.x; i < KTOP; i += 256) {
    float2 v = cf[i];
    float m = fmaxf(v.x, v.y);
    float e0 = crexpf(v.x - m);
    float e1 = crexpf(v.y - m);
    float s = e1 / (e0 + e1);          // exact f32 steps (validated)
    int idx = c * KTOP + i;
    ks[i] = ((u64)__float_as_uint(s) << 15) | (u64)(NPRI - 1 - idx);
  }
  for (int k = 2; k <= KTOP; k <<= 1) {
    for (int j = k >> 1; j > 0; j >>= 1) {
      __syncthreads();
      for (int l = threadIdx.x; l < KTOP; l += 256) {
        int p = l ^ j;
        if (p > l) {
          u64 a = ks[l], q = ks[p];
          bool up = ((l & k) == 0);
          if ((a > q) != up) { ks[l] = q; ks[p] = a; }
        }
      }
    }
  }
  __syncthreads();
  u64* dst = keyG + (size_t)b * NPRI + (size_t)c * KTOP;
  for (int i = threadIdx.x; i < KTOP; i += 256) dst[i] = ks[i];
}

// K2: 3 blocks/image: serially merge 7 runs -> top-1024 (r17-validated).
__global__ __launch_bounds__(256) void k_merge7(const u64* __restrict__ keyG,
                                                u64* __restrict__ midG) {
  const int b = blockIdx.x / 3;
  const int p3 = blockIdx.x % 3;
  __shared__ u64 A[KTOP];
  __shared__ u64 Bv[KTOP];
  const u64* src = keyG + ((size_t)b * NCH + p3 * 7) * KTOP;
  for (int i = threadIdx.x; i < KTOP; i += 256) A[i] = src[i];
  for (int c = 1; c < 7; c++) {
    __syncthreads();
    for (int i = threadIdx.x; i < KTOP; i += 256)
      Bv[i] = src[(size_t)c * KTOP + (KTOP - 1 - i)];   // reversed: asc
    __syncthreads();
    for (int i = threadIdx.x; i < KTOP; i += 256)
      if (Bv[i] > A[i]) A[i] = Bv[i];                    // half-cleaner
    for (int j = KTOP / 2; j > 0; j >>= 1) {             // clean -> desc
      __syncthreads();
      for (int l = threadIdx.x; l < KTOP; l += 256) {
        int p = l ^ j;
        if (p > l) {
          u64 a = A[l], q = A[p];
          if (a < q) { A[l] = q; A[p] = a; }
        }
      }
    }
  }
  __syncthreads();
  u64* d = midG + ((size_t)b * 3 + p3) * KTOP;
  for (int i = threadIdx.x; i < KTOP; i += 256) d[i] = A[i];
}

// K3: per image: merge 3 mids -> top-1024, then validated decode + valid-ballot.
__global__ __launch_bounds__(256) void k_merge3(const u64* __restrict__ midG,
                                                const float* __restrict__ locs,
                                                const float* __restrict__ priors,
                                                float* __restrict__ boxF,
                                                float* __restrict__ scoreF,
                                                u64* __restrict__ validW) {
  const int b = blockIdx.x;
  const int t = threadIdx.x;
  __shared__ u64 A[KTOP];
  __shared__ u64 Bv[KTOP];
  const u64* src = midG + (size_t)b * 3 * KTOP;
  for (int i = t; i < KTOP; i += 256) A[i] = src[i];
  for (int c = 1; c < 3; c++) {
    __syncthreads();
    for (int i = t; i < KTOP; i += 256)
      Bv[i] = src[(size_t)c * KTOP + (KTOP - 1 - i)];
    __syncthreads();
    for (int i = t; i < KTOP; i += 256)
      if (Bv[i] > A[i]) A[i] = Bv[i];
    for (int j = KTOP / 2; j > 0; j >>= 1) {
      __syncthreads();
      for (int l = t; l < KTOP; l += 256) {
        int p = l ^ j;
        if (p > l) {
          u64 a = A[l], q = A[p];
          if (a < q) { A[l] = q; A[p] = a; }
        }
      }
    }
  }
  __syncthreads();
  // decode top-1024: f32-stepwise (identical expressions to validated round 7)
  for (int i = t; i < KTOP; i += 256) {
    u64 K = A[i];
    float sv = __uint_as_float((u32)(K >> 15));
    int idx = NPRI - 1 - (int)(K & 0x7FFFu);
    float4 lo = ((const float4*)locs)[(size_t)b * NPRI + idx];
    float4 pr = ((const float4*)priors)[idx];
    float cx = pr.x + (lo.x * 0.1f) * pr.z;
    float cy = pr.y + (lo.y * 0.1f) * pr.w;
    float w  = pr.z * crexpf(lo.z * 0.2f);
    float h  = pr.w * crexpf(lo.w * 0.2f);
    float x1 = cx - w * 0.5f;
    float y1 = cy - h * 0.5f;
    float x2 = x1 + w;
    float y2 = y1 + h;
    size_t o = (size_t)b * KTOP + i;
    boxF[o * 4 + 0] = x1;
    boxF[o * 4 + 1] = y1;
    boxF[o * 4 + 2] = x2;
    boxF[o * 4 + 3] = y2;
    scoreF[o] = sv;
    u64 mask = __ballot(sv > 0.5f);       // wave covers group i>>6
    if ((t & 63) == 0) validW[(size_t)b * 16 + (i >> 6)] = mask;
  }
}

// K4: upper-triangle suppression bitmask (r13/r17-validated IoU bits), now:
//  - PACKED rows: group g row length (16-g) words -> 68 KB/image;
//  - XCD-affinity 1D grid: all 40 tasks of image b at blockIdx = (b%8) +
//    8*(40*(b/8) + task)  =>  blockIdx % 8 == b % 8 == k_scan's XCD slot,
//    so image b's sup stays in its XCD L2 (heuristic; correctness unaffected).
__global__ __launch_bounds__(256) void k_iou(const float* __restrict__ boxF,
                                             u64* __restrict__ supP) {
  const int bid = blockIdx.x;
  const int x8 = bid & 7;
  const int q = bid >> 3;
  const int bslot = q / 40;
  int task = q - bslot * 40;           // 0..39
  const int b = bslot * 8 + x8;        // image
  int g = 0, base = 0;
  for (int gg = 0; gg < 16; gg++) {
    int cg = (16 - gg + 3) >> 2;
    if (task < base + cg) { g = gg; break; }
    base += cg;
  }
  const int c = task - base;
  const int w0 = g + 4 * c;            // first word of this chunk
  __shared__ float4 BXS[256];
  __shared__ float ARS[256];
  const float4* bb = (const float4*)(boxF + (size_t)b * KTOP * 4);
  {
    int j = w0 * 64 + threadIdx.x;
    if (j < KTOP) {
      float4 v = bb[j];
      BXS[threadIdx.x] = v;
      ARS[threadIdx.x] = fmaxf(v.z - v.x, 0.0f) * fmaxf(v.w - v.y, 0.0f);
    }
  }
  const int r = threadIdx.x & 63;
  const int v = threadIdx.x >> 6;      // wave 0..3
  const int i = g * 64 + r;
  float4 bi = bb[i];
  float a = fmaxf(bi.z - bi.x, 0.0f) * fmaxf(bi.w - bi.y, 0.0f);
  __syncthreads();
  const int w = w0 + v;
  if (w < 16) {
    u64 word = 0;
    const int lbase = v * 64;
    for (int jb = 0; jb < 64; jb++) {
      int lj = lbase + jb;
      float4 bj = BXS[lj];             // broadcast (w uniform in wave)
      float aj = ARS[lj];
      float lx = fmaxf(bi.x, bj.x);
      float ly = fmaxf(bi.y, bj.y);
      float rx = fminf(bi.z, bj.z);
      float ry = fminf(bi.w, bj.w);
      float iw = fmaxf(rx - lx, 0.0f);
      float ih = fmaxf(ry - ly, 0.0f);
      float inter = iw * ih;
      float uni = (a + aj) - inter;
      float iou = inter / fmaxf(uni, 1e-9f);
      if (iou > 0.4f) word |= (1ULL << jb);
    }
    if (w == g) word &= (r == 63) ? 0ULL : (~0ULL << (r + 1));   // j > i
    supP[(size_t)b * SUPW + supBase(g) + (size_t)r * (16 - g) + (w - g)] = word;
  }
}

// K5: greedy scan v6 — packed 68 KB sup async-DMA'd to LDS (global_load_lds
// width=16, 68 chunks of 1 KB), then the r12-validated chain + OR run with
// zero global access. Same bits, packed LDS indexing.
__global__ __launch_bounds__(256) void k_scan(const u64* __restrict__ supP,
                                              const u64* __restrict__ validW,
                                              const float* __restrict__ boxF,
                                              const float* __restrict__ scoreF,
                                              float* __restrict__ out) {
  extern __shared__ u64 rows[];        // SUPW u64 = 69632 B
  const int b = blockIdx.x;
  const int t = threadIdx.x;
  const int lane = t & 63;
  const int wv = t >> 6;               // wave 0..3
  __shared__ u64 keepW[16], vW[16], remv[16];
  const u64* supB = supP + (size_t)b * SUPW;
  // async bulk stage: 68 chunks x 1 KB
  {
    const unsigned char* gb = (const unsigned char*)supB;
    unsigned char* lb = (unsigned char*)rows;
    for (int c = wv; c < 68; c += 4) {
      int off = c << 10;
      __builtin_amdgcn_global_load_lds(
          (const __attribute__((address_space(1))) unsigned int*)(gb + off + lane * 16),
          (__attribute__((address_space(3))) unsigned int*)(lb + off),
          16, 0, 0);
    }
  }
  if (t < 16) { remv[t] = 0; vW[t] = validW[(size_t)b * 16 + t]; }
  __syncthreads();                     // drains vmcnt
  for (int g = 0; g < 16; g++) {
    const int rb = supBase(g);
    const int rl = 16 - g;
    if (t < 64) {
      u64 diag = rows[rb + lane * rl];             // word w==g (packed offset 0)
      u64 alive = vW[g] & ~remv[g];                // wave-uniform
      u64 keep = 0, m = alive;
      while (m) {
        int i = __builtin_ctzll(m);
        keep |= (1ULL << i);
        alive &= ~readlane64(diag, i);             // row i has only bits j>i
        m = (i == 63) ? 0ULL : (alive & (~0ULL << (i + 1)));
      }
      if (lane == 0) keepW[g] = keep;
    }
    __syncthreads();
    // OR kept rows into removal words of future groups (pure LDS, packed)
    {
      u64 kw = keepW[g];
      int w = t & 15;
      if (w > g) {
        int i0 = (t >> 4) * 4;
        u64 acc = 0;
        for (int i = i0; i < i0 + 4; i++)
          if ((kw >> i) & 1ULL) acc |= rows[rb + i * rl + (w - g)];
        if (acc) atomicOr(&remv[w], acc);
      }
    }
    __syncthreads();   // remv visible for next group's chain
  }
  const float* bb = boxF + (size_t)b * KTOP * 4;
  const float* sc = scoreF + (size_t)b * KTOP;
  for (int i = t; i < KTOP; i += 256) {
    float kf = ((keepW[i >> 6] >> (i & 63)) & 1ULL) ? 1.0f : 0.0f;
    size_t o5 = ((size_t)b * KTOP + i) * 5;
    out[o5 + 0] = bb[i * 4 + 0] * kf;
    out[o5 + 1] = bb[i * 4 + 1] * kf;
    out[o5 + 2] = bb[i * 4 + 2] * kf;
    out[o5 + 3] = bb[i * 4 + 3] * kf;
    out[o5 + 4] = sc[i] * kf;
    out[(size_t)BATCH * KTOP * 5 + (size_t)b * KTOP + i] = kf;
  }
}

extern "C" void kernel_launch(void* const* d_in, const int* in_sizes, int n_in,
                              void* d_out, int out_size, void* d_ws, size_t ws_size,
                              hipStream_t stream) {
  const float* locs = nullptr;
  const float* confs = nullptr;
  const float* priors = nullptr;
  for (int i = 0; i < n_in; i++) {
    if (in_sizes[i] == BATCH * NPRI * 4) locs = (const float*)d_in[i];
    else if (in_sizes[i] == BATCH * NPRI * 2) confs = (const float*)d_in[i];
    else if (in_sizes[i] == NPRI * 4) priors = (const float*)d_in[i];
  }
  float* out = (float*)d_out;   // f32: [B,K,5] dets ++ [B,K] keep

  char* ws = (char*)d_ws;
  size_t off = 0;
  u64* keyG = (u64*)(ws + off);          // B*21*1024*8 = 11,010,048
  u64* supP = (u64*)(ws + off);          // alias: keyG dead after k_merge7 (4,456,448)
  off += (size_t)BATCH * NCH * KTOP * 8;
  u64* midG = (u64*)(ws + off);          off += (size_t)BATCH * 3 * KTOP * 8;   // 1,572,864
  float* boxF = (float*)(ws + off);      off += (size_t)BATCH * KTOP * 4 * 4;   // 1,048,576
  float* scoreF = (float*)(ws + off);    off += (size_t)BATCH * KTOP * 4;       //   262,144
  u64* validW = (u64*)(ws + off);        off += (size_t)BATCH * 16 * 8;         //     8,192
  // total ~13.9 MB

  k_sort<<<BATCH * NCH, 256, 0, stream>>>(confs, keyG);
  k_merge7<<<BATCH * 3, 256, 0, stream>>>(keyG, midG);
  k_merge3<<<BATCH, 256, 0, stream>>>(midG, locs, priors, boxF, scoreF, validW);
  k_iou<<<2560, 256, 0, stream>>>(boxF, supP);
  k_scan<<<BATCH, 256, SUPW * 8, stream>>>(supP, validW, boxF, scoreF, out);
}